// Round 6
// baseline (159.275 us; speedup 1.0000x reference)
//
#include <hip/hip_runtime.h>

// DCN: B=4, C=64, H=W=128, Cout=64, 3x3, pad=1, stride=1, dil=1
#define B_   4
#define C_   64
#define H_   128
#define W_   128
#define OC_  64
#define K_   9
#define OCH_ 18
#define CK_  576

#define S_    104            // Pl row stride in halfs (208 B, 16B-aligned)
#define WCOLS 768            // 8 chunks * 96 padded cols
#define XSW   72             // window cols (64 + 2*4 halo)
#define XSH   7              // window rows (ho-3 .. ho+3)
#define PWIN2 (XSH*XSW)      // 504 half2 (u32) per pair, phase-2 window
#define PWIN1 (3*XSW)        // 216 half2 (u32) per pair, phase-1 window
#define CH2   (4*PWIN2)      // 2016 u32 per phase-2 chunk buffer (8064 B)
#define CH1   (4*PWIN1)      //  864 u32 per phase-1 chunk buffer (3456 B)
#define XSTOT (2*CH2)        // 4032 u32 staging region (16128 B)
#define NS1   216            // phase-1 16B slots per chunk (1/thread)
#define NS2   504            // phase-2 16B slots per chunk (2/thread)

#define WPAD_HALFS  (OC_*WCOLS)              // 49152
#define W0PAD_HALFS (32*WCOLS)               // 24576
#define ZPAGE_BYTE  (2*WPAD_HALFS + 2*W0PAD_HALFS)   // 147456 (16B aligned)
#define XH_BYTE     (ZPAGE_BYTE + 256)               // 147712 (16B aligned)
// xh: pair-interleaved f16 copy of x, [b][pair][y][x] as half2 -> 8 MB in d_ws.
// REQUIRES ws_size >= XH_BYTE + 8 MB.

using half8v  = __attribute__((ext_vector_type(8))) _Float16;
using half2v  = __attribute__((ext_vector_type(2))) _Float16;
using float4v = __attribute__((ext_vector_type(4))) float;

// async 16B global->LDS DMA (no VGPR round-trip; drained by vmcnt at barriers)
#define GLDS16(SRC, DST)                                              \
    __builtin_amdgcn_global_load_lds(                                 \
        (__attribute__((address_space(1))) void*)(SRC),               \
        (__attribute__((address_space(3))) void*)(DST), 16, 0, 0)

// ---------------------------------------------------------------------------
// k0: cast+pad weights to f16 in MFMA-chunk layout; zero the OOB page.
// ---------------------------------------------------------------------------
__global__ void k0_prep(const float* __restrict__ w, const float* __restrict__ ow,
                        _Float16* __restrict__ wpad, _Float16* __restrict__ w0pad,
                        float* __restrict__ zp) {
    if (blockIdx.x == 0 && threadIdx.x < 64) zp[threadIdx.x] = 0.f;
    int i = blockIdx.x * 256 + threadIdx.x;
    if (i < OC_ * WCOLS) {
        int oc = i / WCOLS, col = i - oc * WCOLS;
        int cc = col / 96, r = col - cc * 96;
        int kk = r >> 3, cl = r & 7;
        float v = 0.f;
        if (kk < 9) v = w[oc * CK_ + (cc * 8 + cl) * 9 + kk];
        wpad[i] = (_Float16)v;
    } else {
        int j = i - OC_ * WCOLS;
        if (j < 32 * WCOLS) {
            int rr = j / WCOLS, col = j - rr * WCOLS;
            int cc = col / 96, r = col - cc * 96;
            int kk = r >> 3, cl = r & 7;
            float v = 0.f;
            if (rr < OCH_ && kk < 9) v = ow[rr * CK_ + (cc * 8 + cl) * 9 + kk];
            w0pad[j] = (_Float16)v;
        }
    }
}

// ---------------------------------------------------------------------------
// k1: x (f32 NCHW) -> xh (f16 channel-PAIR-interleaved): dword = (ch2p, ch2p+1)
// at one position. One b32 LDS read then serves BOTH channels of a bilinear
// corner (halves the dominant DS-read term in k_fused).
// ---------------------------------------------------------------------------
__global__ void k1_prep(const float* __restrict__ x, unsigned* __restrict__ xh) {
    int i = blockIdx.x * 256 + threadIdx.x;      // [0, 524288): 4 pos each
    int bp = i >> 12;                            // b*32 + pair
    int j  = (i & 4095) * 4;
    int b = bp >> 5, p = bp & 31;
    const float* c0 = x + (((long)(b * 64 + 2 * p)) << 14) + j;
    const float* c1 = c0 + (1 << 14);
    float4v v0 = *(const float4v*)c0;
    float4v v1 = *(const float4v*)c1;
    half8v hv;
#pragma unroll
    for (int k = 0; k < 4; k++) {
        hv[2 * k]     = (_Float16)v0[k];
        hv[2 * k + 1] = (_Float16)v1[k];
    }
    *(half8v*)(xh + ((long)bp << 14) + j) = hv;
}

// ---------------------------------------------------------------------------
// k_fused: phase1 offset conv + phase2 bilinear sample + main conv, both
// staging from xh (f16 pair-interleaved) via async DMA double buffers.
//  - phase-1 im2col = pure b32 copy (both channels per read, no cvt);
//    rounding identical to prior f32->f16 at Pl.
//  - phase-2: 36 b32 sample reads/chunk (was 72 f32), full-chunk double
//    buffer (8064 B each) -> 2 barriers/chunk (was 3).
//  - Pl writes b32 (the 7.28M-conflict regime, r5-verified).
// LDS = 16128 + 13312 + 4608 = 34048 B -> 4 blocks/CU (r2/r4-proven bound;
// r5 showed 40960 does NOT fit 4). Grid = 4/CU: single occupancy round.
// ---------------------------------------------------------------------------
__global__ __launch_bounds__(256, 3) void k_fused(
    const float* __restrict__ x, const unsigned* __restrict__ xh,
    const _Float16* __restrict__ wpad, const _Float16* __restrict__ w0pad,
    const float* __restrict__ bias, const float* __restrict__ ob,
    const float* __restrict__ zp, float* __restrict__ out)
{
    __shared__ __align__(16) unsigned xs1[XSTOT];    // 16128 B staging region
    __shared__ __align__(16) _Float16 Pl[64 * S_];   // 13312 B
    __shared__ float offs_lds[OCH_ * 64];            //  4608 B

    // ---- XCD-aware work decode ----
    const int g   = blockIdx.x;
    const int xcd = g & 7;
    const int n   = g >> 3;
    const int hb  = n & 1;
    const int hol = (n >> 1) & 15;
    const int b   = n >> 5;
    const int ho  = xcd * 16 + hol;

    const int t = threadIdx.x, lane = t & 63, w = t >> 6;
    const int lr = lane & 15, q = lane >> 4;
    const int lpix = w * 16 + lr;            // this thread's pixel
    const int po   = hb * 64 + lpix;
    const int start = hb * 64 - 4;
    const float*    xb  = x  + ((long)b << 20);
    const unsigned* xhb = xh + ((long)b << 19);      // 32 pairs * 16384
    const unsigned* zpu = (const unsigned*)zp;

    // zero Pl pad cols 72..95 once
    for (int i = t; i < 64 * 12; i += 256) {
        int row = i / 12, j = i - row * 12;
        *(unsigned*)&Pl[row * S_ + 72 + 2 * j] = 0u;
    }

    // ---- staging slot descriptors (decoded once; offsets in u32 units) ----
    // phase-1: 4 pairs x rows ho-1..ho+1 x 18 col-slots (216 slots, 1/thread)
    int g1o; bool g1k; const bool g1v = t < NS1;
    {
        int ii = g1v ? t : 0;
        int pr = ii / 54, rj = ii - pr * 54;
        int r3 = rj / 18, jc = rj - r3 * 18;
        int gy = ho - 1 + r3, gx = start + 4 * jc;
        g1k = ((unsigned)gy < (unsigned)H_) && (gx >= 0) && (gx + 3 < W_);
        g1o = (pr << 14) + (gy << 7) + gx;
    }
    // phase-2: 4 pairs x rows ho-3..ho+3 x 18 col-slots (504 slots, 2/thread)
    int g2o[2]; bool g2k[2], g2v[2];
#pragma unroll
    for (int s = 0; s < 2; s++) {
        int idx = t + 256 * s;
        g2v[s] = idx < NS2;
        int ii = g2v[s] ? idx : 0;
        int pr = ii / 126, rj = ii - pr * 126;
        int r  = rj / 18, jc = rj - r * 18;
        int gy = ho - 3 + r, gx = start + 4 * jc;
        g2k[s] = ((unsigned)gy < (unsigned)H_) && (gx >= 0) && (gx + 3 < W_);
        g2o[s] = (pr << 14) + (gy << 7) + gx;
    }

    // ================= phase 1: offset conv =================
    if (g1v) GLDS16(g1k ? (xhb + g1o) : zpu, xs1 + 4 * t);   // chunk 0 -> buf0

    float4v oa0 = {0.f,0.f,0.f,0.f}, oa1 = {0.f,0.f,0.f,0.f};

    for (int cc = 0; cc < 8; cc++) {
        __syncthreads();                       // (A) buf[cc&1] ready (drains DMA)
        if (cc < 7) {
            unsigned* dst = xs1 + ((cc + 1) & 1) * CH1;
            const unsigned* srcb = xhb + ((long)(cc + 1) << 16);  // +4 pairs
            if (g1v) GLDS16(g1k ? (srcb + g1o) : zpu, dst + 4 * t);
        }
        // im2col: pure b32 copy (channels 2q,2q+1 packed) at pixel lpix
        {
            const unsigned* b0 = xs1 + (cc & 1) * CH1 + q * PWIN1;
#pragma unroll
            for (int ky = 0; ky < 3; ky++) {
#pragma unroll
                for (int kx = 0; kx < 3; kx++) {
                    *(unsigned*)&Pl[lpix * S_ + (ky * 3 + kx) * 8 + 2 * q] =
                        b0[ky * XSW + lpix + 3 + kx];
                }
            }
        }
        __syncthreads();                       // (B) Pl ready (drains stage cc+1)
#pragma unroll
        for (int ks = 0; ks < 3; ks++) {
            half8v a0 = *(const half8v*)&w0pad[lr * WCOLS + cc * 96 + ks * 32 + q * 8];
            half8v a1 = *(const half8v*)&w0pad[(16 + lr) * WCOLS + cc * 96 + ks * 32 + q * 8];
            half8v bv = *(const half8v*)&Pl[lpix * S_ + ks * 32 + q * 8];
            oa0 = __builtin_amdgcn_mfma_f32_16x16x32_f16(a0, bv, oa0, 0, 0, 0);
            oa1 = __builtin_amdgcn_mfma_f32_16x16x32_f16(a1, bv, oa1, 0, 0, 0);
        }
    }

    // offsets -> LDS
#pragma unroll
    for (int r = 0; r < 4; r++) {
        int ch = q * 4 + r;
        offs_lds[ch * 64 + lpix] = oa0[r] + ob[ch];
    }
#pragma unroll
    for (int r = 0; r < 4; r++) {
        int ch = 16 + q * 4 + r;
        if (ch < OCH_) offs_lds[ch * 64 + lpix] = oa1[r] + ob[ch];
    }
    __syncthreads();                           // (C) offs ready; phase-1 xs reads done

    // phase-2 prologue: issue chunk-0 DMA, then meta (overlaps DMA latency)
#pragma unroll
    for (int s = 0; s < 2; s++) if (g2v[s])
        GLDS16(g2k[s] ? (xhb + g2o[s]) : zpu, xs1 + 4 * (t + 256 * s));

    unsigned moff[9];
    float mw0[9], mw1[9], mw2[9], mw3[9];
    unsigned okm = 0;
#pragma unroll
    for (int kk = 0; kk < 9; kk++) {
        int ky = kk / 3, kx = kk - 3 * ky;
        float dy = offs_lds[(2 * kk) * 64 + lpix];
        float dx = offs_lds[(2 * kk + 1) * 64 + lpix];
        float py = (float)(ho - 1 + ky) + dy;
        float px = (float)(po - 1 + kx) + dx;
        float fy = floorf(py), fx = floorf(px);
        float ly = py - fy, lx = px - fx;
        int y0 = (int)fy, x0 = (int)fx;
        int y1 = y0 + 1, x1 = x0 + 1;
        float vy0 = ((unsigned)y0 < (unsigned)H_) ? 1.f : 0.f;
        float vy1 = ((unsigned)y1 < (unsigned)H_) ? 1.f : 0.f;
        float vx0 = ((unsigned)x0 < (unsigned)W_) ? 1.f : 0.f;
        float vx1 = ((unsigned)x1 < (unsigned)W_) ? 1.f : 0.f;
        float w00 = (1.f - ly) * (1.f - lx) * vy0 * vx0;
        float w01 = (1.f - ly) * lx * vy0 * vx1;
        float w10 = ly * (1.f - lx) * vy1 * vx0;
        float w11 = ly * lx * vy1 * vx1;
        int cy0 = min(max(y0, 0), H_ - 1);
        int cy1 = min(max(y1, 0), H_ - 1);
        int xl  = min(max(x0, 0), W_ - 2);
        bool noswap = (x0 == xl);              // fold x-clamp into weight swap
        mw0[kk] = noswap ? w00 : w01;
        mw1[kk] = noswap ? w01 : w00;
        mw2[kk] = noswap ? w10 : w11;
        mw3[kk] = noswap ? w11 : w10;
        int sy0 = cy0 - (ho - 3);
        int sy1 = cy1 - (ho - 3);
        int sx  = xl - start;
        bool ok = ((unsigned)sy0 < (unsigned)XSH) && ((unsigned)sy1 < (unsigned)XSH)
               && ((unsigned)sx < (unsigned)(XSW - 1));
        okm |= (ok ? 1u : 0u) << kk;
        // clamp so the speculative LDS read is always in-window; not-ok lanes
        // get overwritten by the per-tap global fallback (execz-skipped).
        int syc0 = min(max(sy0, 0), XSH - 1);
        int syc1 = min(max(sy1, 0), XSH - 1);
        int sxc  = min(max(sx, 0), XSW - 2);
        moff[kk] = (unsigned)(syc0 * XSW + sxc) | ((unsigned)(syc1 * XSW + sxc) << 16);
    }
    __syncthreads();                           // (P) chunk-0 DMA complete

    // ================= phase 2: sample + main conv =================
    // Per chunk: issue next-chunk DMA -> sample pair q (both channels per
    // b32 read) -> (Y) Pl ready -> MFMA -> (X) Pl consumed. 2 barriers/chunk.
    float4v a00 = {0.f,0.f,0.f,0.f}, a01 = {0.f,0.f,0.f,0.f};
    float4v a10 = {0.f,0.f,0.f,0.f}, a11 = {0.f,0.f,0.f,0.f};
    const int wm = w & 1, wn = w >> 1;

    for (int cc = 0; cc < 8; cc++) {
        if (cc < 7) {                          // issue chunk cc+1 -> other buf
            unsigned* dst = xs1 + ((cc + 1) & 1) * CH2;
            const unsigned* srcb = xhb + ((long)(cc + 1) << 16);
#pragma unroll
            for (int s = 0; s < 2; s++) if (g2v[s])
                GLDS16(g2k[s] ? (srcb + g2o[s]) : zpu, dst + 4 * (t + 256 * s));
        }
        // sample channels 2q,2q+1 (pair q) at pixel lpix
        {
            const half2v* bp = (const half2v*)(xs1 + (cc & 1) * CH2) + q * PWIN2;
            const float* xc0 = xb + ((long)(cc * 8 + 2 * q) << 14);
            const float* xc1 = xc0 + (1 << 14);
#pragma unroll
            for (int kk = 0; kk < 9; kk++) {
                int A  = (int)(moff[kk] & 0xFFFFu);
                int Bo = (int)(moff[kk] >> 16);
                half2v d00 = bp[A],  d01 = bp[A + 1];
                half2v d10 = bp[Bo], d11 = bp[Bo + 1];
                float p0 = (float)d00[0] * mw0[kk] + (float)d01[0] * mw1[kk]
                         + (float)d10[0] * mw2[kk] + (float)d11[0] * mw3[kk];
                float p1 = (float)d00[1] * mw0[kk] + (float)d01[1] * mw1[kk]
                         + (float)d10[1] * mw2[kk] + (float)d11[1] * mw3[kk];
                if (__builtin_expect(!((okm >> kk) & 1u), 0)) {
                    // rare big-offset lane: gather from global f32 (clamped)
                    int ky = kk / 3, kx = kk - 3 * ky;
                    float dy = offs_lds[(2 * kk) * 64 + lpix];
                    float dx = offs_lds[(2 * kk + 1) * 64 + lpix];
                    float py = (float)(ho - 1 + ky) + dy;
                    float px = (float)(po - 1 + kx) + dx;
                    int y0 = (int)floorf(py), xq0 = (int)floorf(px);
                    int cy0 = min(max(y0, 0), H_ - 1);
                    int cy1 = min(max(y0 + 1, 0), H_ - 1);
                    int xl  = min(max(xq0, 0), W_ - 2);
                    int ga = (cy0 << 7) + xl, gb = (cy1 << 7) + xl;
                    p0 = xc0[ga] * mw0[kk] + xc0[ga + 1] * mw1[kk]
                       + xc0[gb] * mw2[kk] + xc0[gb + 1] * mw3[kk];
                    p1 = xc1[ga] * mw0[kk] + xc1[ga + 1] * mw1[kk]
                       + xc1[gb] * mw2[kk] + xc1[gb + 1] * mw3[kk];
                }
                half2v hv = {(_Float16)p0, (_Float16)p1};
                *(half2v*)&Pl[lpix * S_ + kk * 8 + 2 * q] = hv;
            }
        }
        __syncthreads();                       // (Y) Pl ready (drains DMA cc+1)
#pragma unroll
        for (int ks = 0; ks < 3; ks++) {
            half8v A0 = *(const half8v*)&wpad[(wm * 32 + lr) * WCOLS + cc * 96 + ks * 32 + q * 8];
            half8v A1 = *(const half8v*)&wpad[(wm * 32 + 16 + lr) * WCOLS + cc * 96 + ks * 32 + q * 8];
            half8v B0 = *(const half8v*)&Pl[(wn * 32 + lr) * S_ + ks * 32 + q * 8];
            half8v B1 = *(const half8v*)&Pl[(wn * 32 + 16 + lr) * S_ + ks * 32 + q * 8];
            a00 = __builtin_amdgcn_mfma_f32_16x16x32_f16(A0, B0, a00, 0, 0, 0);
            a01 = __builtin_amdgcn_mfma_f32_16x16x32_f16(A0, B1, a01, 0, 0, 0);
            a10 = __builtin_amdgcn_mfma_f32_16x16x32_f16(A1, B0, a10, 0, 0, 0);
            a11 = __builtin_amdgcn_mfma_f32_16x16x32_f16(A1, B1, a11, 0, 0, 0);
        }
        if (cc < 7) __syncthreads();           // (X) Pl consumed before next sample
    }

    // ---- epilogue ----
    const int pixc = hb * 64 + wn * 32 + lr;
#pragma unroll
    for (int r = 0; r < 4; r++) {
        int oc0 = wm * 32 + q * 4 + r;
        int oc1 = oc0 + 16;
        float* o0 = out + (((long)(b * OC_ + oc0)) << 14) + (ho << 7);
        float* o1 = out + (((long)(b * OC_ + oc1)) << 14) + (ho << 7);
        o0[pixc]      = a00[r] + bias[oc0];
        o0[pixc + 16] = a01[r] + bias[oc0];
        o1[pixc]      = a10[r] + bias[oc1];
        o1[pixc + 16] = a11[r] + bias[oc1];
    }
}

// ---------------------------------------------------------------------------
extern "C" void kernel_launch(void* const* d_in, const int* in_sizes, int n_in,
                              void* d_out, int out_size, void* d_ws, size_t ws_size,
                              hipStream_t stream) {
    const float* x  = (const float*)d_in[0];
    const float* wt = (const float*)d_in[1];
    const float* bi = (const float*)d_in[2];
    const float* ow = (const float*)d_in[3];
    const float* ob = (const float*)d_in[4];
    float* out = (float*)d_out;

    _Float16* wpad  = (_Float16*)d_ws;
    _Float16* w0pad = wpad + WPAD_HALFS;
    float*    zp    = (float*)((char*)d_ws + ZPAGE_BYTE);
    unsigned* xh    = (unsigned*)((char*)d_ws + XH_BYTE);   // 8 MB

    k0_prep<<<(OC_ * WCOLS + 32 * WCOLS + 255) / 256, 256, 0, stream>>>(wt, ow, wpad, w0pad, zp);
    k1_prep<<<2048, 256, 0, stream>>>(x, xh);
    k_fused<<<B_ * H_ * 2, 256, 0, stream>>>(x, xh, wpad, w0pad, bi, ob, zp, out);
}

// Round 7
// 153.390 us; speedup vs baseline: 1.0384x; 1.0384x over previous
//
#include <hip/hip_runtime.h>

// DCN: B=4, C=64, H=W=128, Cout=64, 3x3, pad=1, stride=1, dil=1
#define B_   4
#define C_   64
#define H_   128
#define W_   128
#define OC_  64
#define K_   9
#define OCH_ 18
#define CK_  576

#define S_    104            // Pl row stride in halfs (208 B, 16B-aligned)
#define WCOLS 768            // 8 chunks * 96 padded cols
#define XSW   72             // window cols (64 + 2*4 halo)
#define XSH   7              // window rows (ho-3 .. ho+3)
#define PWIN2 (XSH*XSW)      // 504 half2 (u32) per pair, phase-2 window
#define PWIN1 (3*XSW)        // 216 half2 (u32) per pair, phase-1 window
#define CH2   (4*PWIN2)      // 2016 u32 per phase-2 chunk buffer (8064 B)
#define CH1   (4*PWIN1)      //  864 u32 per phase-1 chunk buffer (3456 B)
#define XSTOT (2*CH2)        // 4032 u32 staging region (16128 B)
#define NS1   216            // phase-1 16B slots per chunk (1/thread)
#define NS2   504            // phase-2 16B slots per chunk (2/thread)

#define WPAD_HALFS  (OC_*WCOLS)              // 49152
#define W0PAD_HALFS (32*WCOLS)               // 24576
#define ZPAGE_BYTE  (2*WPAD_HALFS + 2*W0PAD_HALFS)   // 147456 (16B aligned)
#define XH_BYTE     (ZPAGE_BYTE + 256)               // 147712 (16B aligned)
// xh: pair-interleaved f16 copy of x, [b][pair][y][x] as half2 -> 8 MB in d_ws.

using half8v  = __attribute__((ext_vector_type(8))) _Float16;
using half2v  = __attribute__((ext_vector_type(2))) _Float16;
using float4v = __attribute__((ext_vector_type(4))) float;

// async 16B global->LDS DMA (no VGPR round-trip; drained by vmcnt at barriers)
#define GLDS16(SRC, DST)                                              \
    __builtin_amdgcn_global_load_lds(                                 \
        (__attribute__((address_space(1))) void*)(SRC),               \
        (__attribute__((address_space(3))) void*)(DST), 16, 0, 0)

// ---------------------------------------------------------------------------
// k0: cast+pad weights to f16 in MFMA-chunk layout; zero the OOB page.
// ---------------------------------------------------------------------------
__global__ void k0_prep(const float* __restrict__ w, const float* __restrict__ ow,
                        _Float16* __restrict__ wpad, _Float16* __restrict__ w0pad,
                        float* __restrict__ zp) {
    if (blockIdx.x == 0 && threadIdx.x < 64) zp[threadIdx.x] = 0.f;
    int i = blockIdx.x * 256 + threadIdx.x;
    if (i < OC_ * WCOLS) {
        int oc = i / WCOLS, col = i - oc * WCOLS;
        int cc = col / 96, r = col - cc * 96;
        int kk = r >> 3, cl = r & 7;
        float v = 0.f;
        if (kk < 9) v = w[oc * CK_ + (cc * 8 + cl) * 9 + kk];
        wpad[i] = (_Float16)v;
    } else {
        int j = i - OC_ * WCOLS;
        if (j < 32 * WCOLS) {
            int rr = j / WCOLS, col = j - rr * WCOLS;
            int cc = col / 96, r = col - cc * 96;
            int kk = r >> 3, cl = r & 7;
            float v = 0.f;
            if (rr < OCH_ && kk < 9) v = ow[rr * CK_ + (cc * 8 + cl) * 9 + kk];
            w0pad[j] = (_Float16)v;
        }
    }
}

// ---------------------------------------------------------------------------
// k1: x (f32 NCHW) -> xh (f16 channel-PAIR-interleaved): dword = (ch2p, ch2p+1)
// at one position. One b32 LDS read serves BOTH channels of a bilinear corner.
// ---------------------------------------------------------------------------
__global__ void k1_prep(const float* __restrict__ x, unsigned* __restrict__ xh) {
    int i = blockIdx.x * 256 + threadIdx.x;      // [0, 524288): 4 pos each
    int bp = i >> 12;                            // b*32 + pair
    int j  = (i & 4095) * 4;
    int b = bp >> 5, p = bp & 31;
    const float* c0 = x + (((long)(b * 64 + 2 * p)) << 14) + j;
    const float* c1 = c0 + (1 << 14);
    float4v v0 = *(const float4v*)c0;
    float4v v1 = *(const float4v*)c1;
    half8v hv;
#pragma unroll
    for (int k = 0; k < 4; k++) {
        hv[2 * k]     = (_Float16)v0[k];
        hv[2 * k + 1] = (_Float16)v1[k];
    }
    *(half8v*)(xh + ((long)bp << 14) + j) = hv;
}

// ---------------------------------------------------------------------------
// k_fused: phase1 offset conv + phase2 bilinear sample + main conv, staging
// from xh (f16 pair-interleaved) via async DMA double buffers.
//  - phase-2: 36 b32 sample reads/chunk (r6-validated: conflicts 10.5M->6.7M,
//    FETCH 11.6->6.1 MB), full-chunk dbuf, 2 barriers/chunk.
//  - WHOLE-WAVE fallback (r4 style, __all once, branch around the tap loop):
//    r6's per-tap inline fallback cost +24 VGPR (60->84) which crossed the
//    register-file boundary for 4 blocks/CU (3-block two-round profile,
//    95us). Keeping fallback out of the hot loop restores VGPR<=~64.
// LDS = 16128 + 13312 + 4608 = 34048 B -> 4 blocks/CU (proven bound; r5
// showed 40960 fails). Grid = 4/CU: single occupancy round.
// ---------------------------------------------------------------------------
__global__ __launch_bounds__(256, 3) void k_fused(
    const float* __restrict__ x, const unsigned* __restrict__ xh,
    const _Float16* __restrict__ wpad, const _Float16* __restrict__ w0pad,
    const float* __restrict__ bias, const float* __restrict__ ob,
    const float* __restrict__ zp, float* __restrict__ out)
{
    __shared__ __align__(16) unsigned xs1[XSTOT];    // 16128 B staging region
    __shared__ __align__(16) _Float16 Pl[64 * S_];   // 13312 B
    __shared__ float offs_lds[OCH_ * 64];            //  4608 B

    // ---- XCD-aware work decode ----
    const int g   = blockIdx.x;
    const int xcd = g & 7;
    const int n   = g >> 3;
    const int hb  = n & 1;
    const int hol = (n >> 1) & 15;
    const int b   = n >> 5;
    const int ho  = xcd * 16 + hol;

    const int t = threadIdx.x, lane = t & 63, w = t >> 6;
    const int lr = lane & 15, q = lane >> 4;
    const int lpix = w * 16 + lr;            // this thread's pixel
    const int po   = hb * 64 + lpix;
    const int start = hb * 64 - 4;
    const float*    xb  = x  + ((long)b << 20);
    const unsigned* xhb = xh + ((long)b << 19);      // 32 pairs * 16384
    const unsigned* zpu = (const unsigned*)zp;

    // zero Pl pad cols 72..95 once
    for (int i = t; i < 64 * 12; i += 256) {
        int row = i / 12, j = i - row * 12;
        *(unsigned*)&Pl[row * S_ + 72 + 2 * j] = 0u;
    }

    // ---- staging slot descriptors (decoded once; offsets in u32 units) ----
    // phase-1: 4 pairs x rows ho-1..ho+1 x 18 col-slots (216 slots, 1/thread)
    int g1o; bool g1k; const bool g1v = t < NS1;
    {
        int ii = g1v ? t : 0;
        int pr = ii / 54, rj = ii - pr * 54;
        int r3 = rj / 18, jc = rj - r3 * 18;
        int gy = ho - 1 + r3, gx = start + 4 * jc;
        g1k = ((unsigned)gy < (unsigned)H_) && (gx >= 0) && (gx + 3 < W_);
        g1o = (pr << 14) + (gy << 7) + gx;
    }
    // phase-2: 4 pairs x rows ho-3..ho+3 x 18 col-slots (504 slots, 2/thread)
    int g2o[2]; bool g2k[2], g2v[2];
#pragma unroll
    for (int s = 0; s < 2; s++) {
        int idx = t + 256 * s;
        g2v[s] = idx < NS2;
        int ii = g2v[s] ? idx : 0;
        int pr = ii / 126, rj = ii - pr * 126;
        int r  = rj / 18, jc = rj - r * 18;
        int gy = ho - 3 + r, gx = start + 4 * jc;
        g2k[s] = ((unsigned)gy < (unsigned)H_) && (gx >= 0) && (gx + 3 < W_);
        g2o[s] = (pr << 14) + (gy << 7) + gx;
    }

    // ================= phase 1: offset conv =================
    if (g1v) GLDS16(g1k ? (xhb + g1o) : zpu, xs1 + 4 * t);   // chunk 0 -> buf0

    float4v oa0 = {0.f,0.f,0.f,0.f}, oa1 = {0.f,0.f,0.f,0.f};

    for (int cc = 0; cc < 8; cc++) {
        __syncthreads();                       // (A) buf[cc&1] ready (drains DMA)
        if (cc < 7) {
            unsigned* dst = xs1 + ((cc + 1) & 1) * CH1;
            const unsigned* srcb = xhb + ((long)(cc + 1) << 16);  // +4 pairs
            if (g1v) GLDS16(g1k ? (srcb + g1o) : zpu, dst + 4 * t);
        }
        // im2col: pure b32 copy (channels 2q,2q+1 packed) at pixel lpix
        {
            const unsigned* b0 = xs1 + (cc & 1) * CH1 + q * PWIN1;
#pragma unroll
            for (int ky = 0; ky < 3; ky++) {
#pragma unroll
                for (int kx = 0; kx < 3; kx++) {
                    *(unsigned*)&Pl[lpix * S_ + (ky * 3 + kx) * 8 + 2 * q] =
                        b0[ky * XSW + lpix + 3 + kx];
                }
            }
        }
        __syncthreads();                       // (B) Pl ready (drains stage cc+1)
#pragma unroll
        for (int ks = 0; ks < 3; ks++) {
            half8v a0 = *(const half8v*)&w0pad[lr * WCOLS + cc * 96 + ks * 32 + q * 8];
            half8v a1 = *(const half8v*)&w0pad[(16 + lr) * WCOLS + cc * 96 + ks * 32 + q * 8];
            half8v bv = *(const half8v*)&Pl[lpix * S_ + ks * 32 + q * 8];
            oa0 = __builtin_amdgcn_mfma_f32_16x16x32_f16(a0, bv, oa0, 0, 0, 0);
            oa1 = __builtin_amdgcn_mfma_f32_16x16x32_f16(a1, bv, oa1, 0, 0, 0);
        }
    }

    // offsets -> LDS
#pragma unroll
    for (int r = 0; r < 4; r++) {
        int ch = q * 4 + r;
        offs_lds[ch * 64 + lpix] = oa0[r] + ob[ch];
    }
#pragma unroll
    for (int r = 0; r < 4; r++) {
        int ch = 16 + q * 4 + r;
        if (ch < OCH_) offs_lds[ch * 64 + lpix] = oa1[r] + ob[ch];
    }
    __syncthreads();                           // (C) offs ready; phase-1 xs reads done

    // phase-2 prologue: issue chunk-0 DMA, then meta (overlaps DMA latency)
#pragma unroll
    for (int s = 0; s < 2; s++) if (g2v[s])
        GLDS16(g2k[s] ? (xhb + g2o[s]) : zpu, xs1 + 4 * (t + 256 * s));

    unsigned moff[9];
    float mw0[9], mw1[9], mw2[9], mw3[9];
    unsigned okm = 0;
#pragma unroll
    for (int kk = 0; kk < 9; kk++) {
        int ky = kk / 3, kx = kk - 3 * ky;
        float dy = offs_lds[(2 * kk) * 64 + lpix];
        float dx = offs_lds[(2 * kk + 1) * 64 + lpix];
        float py = (float)(ho - 1 + ky) + dy;
        float px = (float)(po - 1 + kx) + dx;
        float fy = floorf(py), fx = floorf(px);
        float ly = py - fy, lx = px - fx;
        int y0 = (int)fy, x0 = (int)fx;
        int y1 = y0 + 1, x1 = x0 + 1;
        float vy0 = ((unsigned)y0 < (unsigned)H_) ? 1.f : 0.f;
        float vy1 = ((unsigned)y1 < (unsigned)H_) ? 1.f : 0.f;
        float vx0 = ((unsigned)x0 < (unsigned)W_) ? 1.f : 0.f;
        float vx1 = ((unsigned)x1 < (unsigned)W_) ? 1.f : 0.f;
        float w00 = (1.f - ly) * (1.f - lx) * vy0 * vx0;
        float w01 = (1.f - ly) * lx * vy0 * vx1;
        float w10 = ly * (1.f - lx) * vy1 * vx0;
        float w11 = ly * lx * vy1 * vx1;
        int cy0 = min(max(y0, 0), H_ - 1);
        int cy1 = min(max(y1, 0), H_ - 1);
        int xl  = min(max(x0, 0), W_ - 2);
        bool noswap = (x0 == xl);              // fold x-clamp into weight swap
        mw0[kk] = noswap ? w00 : w01;
        mw1[kk] = noswap ? w01 : w00;
        mw2[kk] = noswap ? w10 : w11;
        mw3[kk] = noswap ? w11 : w10;
        int sy0 = cy0 - (ho - 3);
        int sy1 = cy1 - (ho - 3);
        int sx  = xl - start;
        bool ok = ((unsigned)sy0 < (unsigned)XSH) && ((unsigned)sy1 < (unsigned)XSH)
               && ((unsigned)sx < (unsigned)(XSW - 1));
        okm |= (ok ? 1u : 0u) << kk;
        moff[kk] = (unsigned)(sy0 * XSW + sx) | ((unsigned)(sy1 * XSW + sx) << 16);
    }
    const bool allok = __all(okm == 0x1FFu);   // whole-wave fast/slow split
    __syncthreads();                           // (P) chunk-0 DMA complete

    // ================= phase 2: sample + main conv =================
    // Per chunk: issue next-chunk DMA -> sample pair q (both channels per
    // b32 read) -> (Y) Pl ready -> MFMA -> (X) Pl consumed. 2 barriers/chunk.
    float4v a00 = {0.f,0.f,0.f,0.f}, a01 = {0.f,0.f,0.f,0.f};
    float4v a10 = {0.f,0.f,0.f,0.f}, a11 = {0.f,0.f,0.f,0.f};
    const int wm = w & 1, wn = w >> 1;

    for (int cc = 0; cc < 8; cc++) {
        if (cc < 7) {                          // issue chunk cc+1 -> other buf
            unsigned* dst = xs1 + ((cc + 1) & 1) * CH2;
            const unsigned* srcb = xhb + ((long)(cc + 1) << 16);
#pragma unroll
            for (int s = 0; s < 2; s++) if (g2v[s])
                GLDS16(g2k[s] ? (srcb + g2o[s]) : zpu, dst + 4 * (t + 256 * s));
        }
        if (allok) {
            // sample channels 2q,2q+1 (pair q) at pixel lpix from LDS window
            const half2v* bp = (const half2v*)(xs1 + (cc & 1) * CH2) + q * PWIN2;
#pragma unroll
            for (int kk = 0; kk < 9; kk++) {
                int A  = (int)(moff[kk] & 0xFFFFu);
                int Bo = (int)(moff[kk] >> 16);
                half2v d00 = bp[A],  d01 = bp[A + 1];
                half2v d10 = bp[Bo], d11 = bp[Bo + 1];
                float p0 = (float)d00[0] * mw0[kk] + (float)d01[0] * mw1[kk]
                         + (float)d10[0] * mw2[kk] + (float)d11[0] * mw3[kk];
                float p1 = (float)d00[1] * mw0[kk] + (float)d01[1] * mw1[kk]
                         + (float)d10[1] * mw2[kk] + (float)d11[1] * mw3[kk];
                half2v hv = {(_Float16)p0, (_Float16)p1};
                *(half2v*)&Pl[lpix * S_ + kk * 8 + 2 * q] = hv;
            }
        } else {
            // rare big-offset wave: gather all taps from global f32 (clamped)
            const float* xc0 = xb + ((long)(cc * 8 + 2 * q) << 14);
            const float* xc1 = xc0 + (1 << 14);
#pragma unroll
            for (int kk = 0; kk < 9; kk++) {
                int ky = kk / 3, kx = kk - 3 * ky;
                float dy = offs_lds[(2 * kk) * 64 + lpix];
                float dx = offs_lds[(2 * kk + 1) * 64 + lpix];
                float py = (float)(ho - 1 + ky) + dy;
                float px = (float)(po - 1 + kx) + dx;
                int y0 = (int)floorf(py), xq0 = (int)floorf(px);
                int cy0 = min(max(y0, 0), H_ - 1);
                int cy1 = min(max(y0 + 1, 0), H_ - 1);
                int xl  = min(max(xq0, 0), W_ - 2);
                int ga = (cy0 << 7) + xl, gb = (cy1 << 7) + xl;
                float p0 = xc0[ga] * mw0[kk] + xc0[ga + 1] * mw1[kk]
                         + xc0[gb] * mw2[kk] + xc0[gb + 1] * mw3[kk];
                float p1 = xc1[ga] * mw0[kk] + xc1[ga + 1] * mw1[kk]
                         + xc1[gb] * mw2[kk] + xc1[gb + 1] * mw3[kk];
                half2v hv = {(_Float16)p0, (_Float16)p1};
                *(half2v*)&Pl[lpix * S_ + kk * 8 + 2 * q] = hv;
            }
        }
        __syncthreads();                       // (Y) Pl ready (drains DMA cc+1)
#pragma unroll
        for (int ks = 0; ks < 3; ks++) {
            half8v A0 = *(const half8v*)&wpad[(wm * 32 + lr) * WCOLS + cc * 96 + ks * 32 + q * 8];
            half8v A1 = *(const half8v*)&wpad[(wm * 32 + 16 + lr) * WCOLS + cc * 96 + ks * 32 + q * 8];
            half8v B0 = *(const half8v*)&Pl[(wn * 32 + lr) * S_ + ks * 32 + q * 8];
            half8v B1 = *(const half8v*)&Pl[(wn * 32 + 16 + lr) * S_ + ks * 32 + q * 8];
            a00 = __builtin_amdgcn_mfma_f32_16x16x32_f16(A0, B0, a00, 0, 0, 0);
            a01 = __builtin_amdgcn_mfma_f32_16x16x32_f16(A0, B1, a01, 0, 0, 0);
            a10 = __builtin_amdgcn_mfma_f32_16x16x32_f16(A1, B0, a10, 0, 0, 0);
            a11 = __builtin_amdgcn_mfma_f32_16x16x32_f16(A1, B1, a11, 0, 0, 0);
        }
        if (cc < 7) __syncthreads();           // (X) Pl consumed before next sample
    }

    // ---- epilogue ----
    const int pixc = hb * 64 + wn * 32 + lr;
#pragma unroll
    for (int r = 0; r < 4; r++) {
        int oc0 = wm * 32 + q * 4 + r;
        int oc1 = oc0 + 16;
        float* o0 = out + (((long)(b * OC_ + oc0)) << 14) + (ho << 7);
        float* o1 = out + (((long)(b * OC_ + oc1)) << 14) + (ho << 7);
        o0[pixc]      = a00[r] + bias[oc0];
        o0[pixc + 16] = a01[r] + bias[oc0];
        o1[pixc]      = a10[r] + bias[oc1];
        o1[pixc + 16] = a11[r] + bias[oc1];
    }
}

// ---------------------------------------------------------------------------
extern "C" void kernel_launch(void* const* d_in, const int* in_sizes, int n_in,
                              void* d_out, int out_size, void* d_ws, size_t ws_size,
                              hipStream_t stream) {
    const float* x  = (const float*)d_in[0];
    const float* wt = (const float*)d_in[1];
    const float* bi = (const float*)d_in[2];
    const float* ow = (const float*)d_in[3];
    const float* ob = (const float*)d_in[4];
    float* out = (float*)d_out;

    _Float16* wpad  = (_Float16*)d_ws;
    _Float16* w0pad = wpad + WPAD_HALFS;
    float*    zp    = (float*)((char*)d_ws + ZPAGE_BYTE);
    unsigned* xh    = (unsigned*)((char*)d_ws + XH_BYTE);   // 8 MB

    k0_prep<<<(OC_ * WCOLS + 32 * WCOLS + 255) / 256, 256, 0, stream>>>(wt, ow, wpad, w0pad, zp);
    k1_prep<<<2048, 256, 0, stream>>>(x, xh);
    k_fused<<<B_ * H_ * 2, 256, 0, stream>>>(x, xh, wpad, w0pad, bi, ob, zp, out);
}